// Round 3
// baseline (197.439 us; speedup 1.0000x reference)
//
#include <hip/hip_runtime.h>
#include <hip/hip_bf16.h>

// Shapes: B=2, C=256, H=W=24 (HW=576), G=16, Cg=16, GRID=25, AC=6400, Mg=400
// Inputs fp32 (per reference setup_inputs), output fp32 (reference returns fp32).
// ws layout (fp32): h1f[16*2*256*576] | pooled[16*2*6400] | aff[16*2*16]

__global__ __launch_bounds__(384) void k1_conv_bn(
    const float* __restrict__ xin,
    const float* __restrict__ W1,
    const float* __restrict__ g1, const float* __restrict__ b1,
    const float* __restrict__ m1, const float* __restrict__ v1,
    float* __restrict__ h1f)
{
    __shared__ __align__(16) float xs[16*728];   // [ci][26 rows][28 pitch], zero-padded
    __shared__ __align__(16) float wl[144*16];   // [(ci*9+k)][co]
    int bid = blockIdx.x;                        // i*32 + b*16 + g
    int i = bid >> 5, b = (bid >> 4) & 1, g = bid & 15;
    int t = threadIdx.x;

    for (int idx = t; idx < 16*728; idx += 384) xs[idx] = 0.f;
    __syncthreads();
    for (int idx = t; idx < 16*576; idx += 384) {
        int ci = idx / 576; int s = idx - ci*576;
        int y = s / 24; int xx = s - y*24;
        xs[ci*728 + (y+1)*28 + (xx+1)] = xin[(b*256 + g*16 + ci)*576 + s];
    }
    for (int idx = t; idx < 2304; idx += 384) {
        int co = idx & 15; int rest = idx >> 4;      // rest = ci*9+k
        int ci = rest / 9; int k = rest - ci*9;
        wl[rest*16 + co] = W1[((i*256 + g*16 + co)*16 + ci)*9 + k];
    }
    __syncthreads();

    int co = t & 15;
    int y  = t >> 4;                 // 0..23, one output row per thread
    int c  = g*16 + co;
    float sc = g1[i*256+c] * rsqrtf(v1[i*256+c] + 1e-5f);
    float bb = b1[i*256+c] - m1[i*256+c] * sc;

    float acc[24];
#pragma unroll
    for (int p = 0; p < 24; p++) acc[p] = 0.f;

    for (int ci = 0; ci < 16; ci++) {
        float w[9];
#pragma unroll
        for (int k = 0; k < 9; k++) w[k] = wl[(ci*9+k)*16 + co];
#pragma unroll
        for (int dy = 0; dy < 3; dy++) {
            const float* r = &xs[ci*728 + (y+dy)*28];
            float rv[26];
#pragma unroll
            for (int jj = 0; jj < 6; jj++) {
                float4 v4 = *(const float4*)&r[jj*4];
                rv[jj*4+0]=v4.x; rv[jj*4+1]=v4.y; rv[jj*4+2]=v4.z; rv[jj*4+3]=v4.w;
            }
            rv[24] = r[24]; rv[25] = r[25];
#pragma unroll
            for (int dx = 0; dx < 3; dx++) {
                float wv = w[dy*3+dx];
#pragma unroll
                for (int p = 0; p < 24; p++) acc[p] = fmaf(rv[p+dx], wv, acc[p]);
            }
        }
    }
    float* op = &h1f[((i*2 + b)*256 + c)*576 + y*24];
#pragma unroll
    for (int p = 0; p < 24; p++) op[p] = fmaxf(fmaf(acc[p], sc, bb), 0.f);
}

// Fused: grouped 1x1 conv (pad=1) + BN + ReLU + 26x26 avg-pool -> pooled[i,b,o]
__global__ __launch_bounds__(256) void k2_pool(
    const float* __restrict__ h1f,
    const float* __restrict__ W2,
    const float* __restrict__ g2, const float* __restrict__ b2,
    const float* __restrict__ m2, const float* __restrict__ v2,
    float* __restrict__ pooled)
{
    __shared__ __align__(16) float hs[576*16];   // [s][j], xor-4 swizzled
    int bid = blockIdx.x;                        // i*32 + b*16 + k
    int i = bid >> 5, b = (bid >> 4) & 1, k = bid & 15;
    int t = threadIdx.x;

    const float* hbase = &h1f[((i*2 + b)*256 + k*16)*576];
    for (int idx = t; idx < 9216; idx += 256) {
        int j = idx / 576; int s = idx - j*576;
        int q = j >> 2, jr = j & 3;
        hs[s*16 + ((q ^ (s & 3)) << 2) + jr] = hbase[j*576 + s];
    }
    __syncthreads();

    int m0 = t;                 // row 0: always valid (t < 256 <= 399)
    bool two = (t < 144);       // row 1: m = t+256 valid for t < 144
    int m1r = t + 256;

    float w0f[16], w1f[16];
    float be0, be1 = 0.f;
    {
        int o = k*400 + m0;
        float s2 = g2[i*6400+o] * rsqrtf(v2[i*6400+o] + 1e-5f);
        be0 = b2[i*6400+o] - m2[i*6400+o] * s2;
        const float* wr = &W2[(i*6400 + o)*16];
#pragma unroll
        for (int j = 0; j < 16; j++) w0f[j] = wr[j] * s2;
    }
    if (two) {
        int o = k*400 + m1r;
        float s2 = g2[i*6400+o] * rsqrtf(v2[i*6400+o] + 1e-5f);
        be1 = b2[i*6400+o] - m2[i*6400+o] * s2;
        const float* wr = &W2[(i*6400 + o)*16];
#pragma unroll
        for (int j = 0; j < 16; j++) w1f[j] = wr[j] * s2;
    } else {
#pragma unroll
        for (int j = 0; j < 16; j++) w1f[j] = 0.f;
    }

    float acc0 = 0.f, acc1 = 0.f;
    for (int sb = 0; sb < 576; sb += 4) {
#pragma unroll
        for (int e = 0; e < 4; e++) {           // compile-time swizzle phase
            const float* hp = &hs[(sb+e)*16];
            float4 hv[4];
            hv[0] = *(const float4*)&hp[0];
            hv[1] = *(const float4*)&hp[4];
            hv[2] = *(const float4*)&hp[8];
            hv[3] = *(const float4*)&hp[12];
            float d0 = be0, d1 = be1;
#pragma unroll
            for (int q = 0; q < 4; q++) {
                int jq = (q ^ e) & 3;           // constant per unrolled iter
                const float* wq0 = &w0f[jq*4];
                const float* wq1 = &w1f[jq*4];
                float4 h = hv[q];
                d0 = fmaf(h.x, wq0[0], d0); d0 = fmaf(h.y, wq0[1], d0);
                d0 = fmaf(h.z, wq0[2], d0); d0 = fmaf(h.w, wq0[3], d0);
                d1 = fmaf(h.x, wq1[0], d1); d1 = fmaf(h.y, wq1[1], d1);
                d1 = fmaf(h.z, wq1[2], d1); d1 = fmaf(h.w, wq1[3], d1);
            }
            acc0 += fmaxf(d0, 0.f);
            acc1 += fmaxf(d1, 0.f);
        }
    }
    const float inv = 1.f / 676.f;              // mean over 26x26 incl. 100 border px
    pooled[(i*2+b)*6400 + k*400 + m0] = (acc0 + 100.f * fmaxf(be0, 0.f)) * inv;
    if (two)
        pooled[(i*2+b)*6400 + k*400 + m1r] = (acc1 + 100.f * fmaxf(be1, 0.f)) * inv;
}

__global__ __launch_bounds__(256) void k3_aff(const float* __restrict__ pooled,
                                              float* __restrict__ aff)
{
    __shared__ float th[400];
    __shared__ float parts[256];
    int bid = blockIdx.x;           // i*2 + b
    int i = bid >> 1;
    int t = threadIdx.x;
    const float* pb = &pooled[bid*6400];
    for (int idx = t; idx < 400; idx += 256) th[idx] = pb[i*400 + idx];
    __syncthreads();
    int l = t >> 4, p = t & 15;
    float sum = 0.f;
    const float* pl = &pb[l*400];
    for (int m = p*25; m < p*25 + 25; m++) sum = fmaf(th[m], pl[m], sum);
    parts[t] = sum;
    __syncthreads();
    if (t < 16) {
        float s = 0.f;
        for (int pp = 0; pp < 16; pp++) s += parts[t*16 + pp];
        aff[bid*16 + t] = s * (1.f/16.f);
    }
}

__global__ __launch_bounds__(256) void k4_out(const float* __restrict__ h1f,
                                              const float* __restrict__ aff,
                                              float* __restrict__ out)
{
    __shared__ float a0[16], a1[16];
    int bid = blockIdx.x;           // i*32 + q*16 + cg
    int i = bid >> 5, q = (bid >> 4) & 1, cg = bid & 15;
    int t = threadIdx.x;
    if (t < 16) a0[t] = aff[(i*2+0)*16 + t];
    else if (t < 32) a1[t-16] = aff[(i*2+1)*16 + (t-16)];
    __syncthreads();
    const float* hb = &h1f[((i*2+q)*256 + cg)*576];
    int ch = i*32 + q*16 + cg;
    for (int s = t; s < 576; s += 256) {
        float acc0 = 0.f, acc1 = 0.f;
#pragma unroll
        for (int k = 0; k < 16; k++) {
            float v = hb[k*9216 + s];
            acc0 = fmaf(a0[k], v, acc0);
            acc1 = fmaf(a1[k], v, acc1);
        }
        out[ch*576 + s]         = acc0;
        out[(512 + ch)*576 + s] = acc1;
    }
}

extern "C" void kernel_launch(void* const* d_in, const int* in_sizes, int n_in,
                              void* d_out, int out_size, void* d_ws, size_t ws_size,
                              hipStream_t stream)
{
    const float* x  = (const float*)d_in[0];
    const float* W1 = (const float*)d_in[1];
    const float* g1 = (const float*)d_in[2];
    const float* b1 = (const float*)d_in[3];
    const float* m1 = (const float*)d_in[4];
    const float* v1 = (const float*)d_in[5];
    const float* W2 = (const float*)d_in[6];
    const float* g2 = (const float*)d_in[7];
    const float* b2 = (const float*)d_in[8];
    const float* m2 = (const float*)d_in[9];
    const float* v2 = (const float*)d_in[10];

    float* h1f    = (float*)d_ws;
    float* pooled = h1f + 16*2*256*576;     // +4,718,592 floats
    float* aff    = pooled + 16*2*6400;     // +204,800 floats

    float* out = (float*)d_out;

    hipLaunchKernelGGL(k1_conv_bn, dim3(512), dim3(384), 0, stream,
                       x, W1, g1, b1, m1, v1, h1f);
    hipLaunchKernelGGL(k2_pool,    dim3(512), dim3(256), 0, stream,
                       h1f, W2, g2, b2, m2, v2, pooled);
    hipLaunchKernelGGL(k3_aff,     dim3(32),  dim3(256), 0, stream,
                       pooled, aff);
    hipLaunchKernelGGL(k4_out,     dim3(512), dim3(256), 0, stream,
                       h1f, aff, out);
}

// Round 5
// 151.707 us; speedup vs baseline: 1.3014x; 1.3014x over previous
//
#include <hip/hip_runtime.h>
#include <hip/hip_bf16.h>

// Shapes: B=2, C=256, H=W=24 (HW=576), G=16, Cg=16, GRID=25, AC=6400, Mg=400
// Inputs fp32, output fp32.
// ws layout (fp32): h1f[16*2*256*576] | pooled[16*2*6400] | aff[16*2*16]

typedef __attribute__((ext_vector_type(8))) short short8;
typedef __attribute__((ext_vector_type(4))) short short4v;
typedef __attribute__((ext_vector_type(4))) float f32x4;

static __device__ __forceinline__ short f2bf(float x) {
    unsigned u = __float_as_uint(x);
    unsigned r = (u + 0x7fffu + ((u >> 16) & 1u)) >> 16;   // RNE
    return (short)r;
}

__global__ __launch_bounds__(384) void k1_conv_bn(
    const float* __restrict__ xin,
    const float* __restrict__ W1,
    const float* __restrict__ g1, const float* __restrict__ b1,
    const float* __restrict__ m1, const float* __restrict__ v1,
    float* __restrict__ h1f)
{
    __shared__ __align__(16) float xs[16*728];   // [ci][26 rows][28 pitch], zero-padded
    __shared__ __align__(16) float wl[144*16];   // [(ci*9+k)][co]
    int bid = blockIdx.x;                        // i*32 + b*16 + g
    int i = bid >> 5, b = (bid >> 4) & 1, g = bid & 15;
    int t = threadIdx.x;

    for (int idx = t; idx < 16*728; idx += 384) xs[idx] = 0.f;
    __syncthreads();
    for (int idx = t; idx < 16*576; idx += 384) {
        int ci = idx / 576; int s = idx - ci*576;
        int y = s / 24; int xx = s - y*24;
        xs[ci*728 + (y+1)*28 + (xx+1)] = xin[(b*256 + g*16 + ci)*576 + s];
    }
    for (int idx = t; idx < 2304; idx += 384) {
        int co = idx & 15; int rest = idx >> 4;      // rest = ci*9+k
        int ci = rest / 9; int k = rest - ci*9;
        wl[rest*16 + co] = W1[((i*256 + g*16 + co)*16 + ci)*9 + k];
    }
    __syncthreads();

    int co = t & 15;
    int y  = t >> 4;                 // 0..23, one output row per thread
    int c  = g*16 + co;
    float sc = g1[i*256+c] * rsqrtf(v1[i*256+c] + 1e-5f);
    float bb = b1[i*256+c] - m1[i*256+c] * sc;

    float acc[24];
#pragma unroll
    for (int p = 0; p < 24; p++) acc[p] = 0.f;

    for (int ci = 0; ci < 16; ci++) {
        float w[9];
#pragma unroll
        for (int k = 0; k < 9; k++) w[k] = wl[(ci*9+k)*16 + co];
#pragma unroll
        for (int dy = 0; dy < 3; dy++) {
            const float* r = &xs[ci*728 + (y+dy)*28];
            float rv[26];
#pragma unroll
            for (int jj = 0; jj < 6; jj++) {
                float4 v4 = *(const float4*)&r[jj*4];
                rv[jj*4+0]=v4.x; rv[jj*4+1]=v4.y; rv[jj*4+2]=v4.z; rv[jj*4+3]=v4.w;
            }
            rv[24] = r[24]; rv[25] = r[25];
#pragma unroll
            for (int dx = 0; dx < 3; dx++) {
                float wv = w[dy*3+dx];
#pragma unroll
                for (int p = 0; p < 24; p++) acc[p] = fmaf(rv[p+dx], wv, acc[p]);
            }
        }
    }
    float* op = &h1f[((i*2 + b)*256 + c)*576 + y*24];
#pragma unroll
    for (int p = 0; p < 24; p++) op[p] = fmaxf(fmaf(acc[p], sc, bb), 0.f);
}

// Fused grouped 1x1 conv (pad=1) + BN + ReLU + 26x26 avg-pool via bf16 MFMA.
// Per block (i,b,k): D = W2'(400x16) * h(16x576) + bias; pool = sum_s relu(D).
__global__ __launch_bounds__(256) void k2_pool_mfma(
    const float* __restrict__ h1f,
    const float* __restrict__ W2,
    const float* __restrict__ g2, const float* __restrict__ b2,
    const float* __restrict__ m2, const float* __restrict__ v2,
    float* __restrict__ pooled)
{
    __shared__ __align__(16) short hsb[576*20];   // [s][j], pitch 20 shorts
    __shared__ __align__(16) short wlb[400*16];   // [m][j] bf16, W2*s2
    __shared__ __align__(16) float psum[4*400];   // per-wave pool partials
    __shared__ __align__(16) float bias_s[400];   // folded BN bias per m

    int bid = blockIdx.x;                        // i*32 + b*16 + k
    int i = bid >> 5, b = (bid >> 4) & 1, k = bid & 15;
    int t = threadIdx.x;

    // --- stage h slice (16 j x 576 s) as bf16, transposed to [s][j] ---
    const float* hbase = &h1f[((i*2 + b)*256 + k*16)*576];
    for (int idx = t; idx < 9216; idx += 256) {
        int j = idx / 576; int s = idx - j*576;
        hsb[s*20 + j] = f2bf(hbase[idx]);        // hbase[j*576+s] == hbase[idx]
    }
    // --- stage W2*s2 as bf16 [m][j]; bias per m ---
    for (int m = t; m < 400; m += 256) {
        int o = i*6400 + k*400 + m;
        float s2 = g2[o] * rsqrtf(v2[o] + 1e-5f);
        bias_s[m] = b2[o] - m2[o] * s2;
        const float4* wr = (const float4*)&W2[o*16];
#pragma unroll
        for (int q = 0; q < 4; q++) {
            float4 wv = wr[q];
            wlb[m*16 + q*4 + 0] = f2bf(wv.x * s2);
            wlb[m*16 + q*4 + 1] = f2bf(wv.y * s2);
            wlb[m*16 + q*4 + 2] = f2bf(wv.z * s2);
            wlb[m*16 + q*4 + 3] = f2bf(wv.w * s2);
        }
    }
    __syncthreads();

    int l = t & 63, w = t >> 6;
    int half = l >> 4;          // quad 0..3 ; quads 2,3 are K-padding (zero)
    int col  = l & 15;

    // --- preload 9 B-fragments for this wave's 144-pixel range ---
    short8 bfr[9];
#pragma unroll
    for (int u = 0; u < 9; u++) {
        if (l < 32) {
            const short* p = &hsb[((w*9 + u)*16 + col)*20 + half*8];
            short4v lo = *(const short4v*)p;
            short4v hi = *(const short4v*)(p + 4);
            short8 f; f[0]=lo.x; f[1]=lo.y; f[2]=lo.z; f[3]=lo.w;
                      f[4]=hi.x; f[5]=hi.y; f[6]=hi.z; f[7]=hi.w;
            bfr[u] = f;
        } else {
            bfr[u] = (short8)0;
        }
    }

    for (int mt = 0; mt < 25; mt++) {
        short8 af = (short8)0;
        if (l < 32)
            af = *(const short8*)&wlb[(mt*16 + col)*16 + half*8];

        // bias as MFMA C-operand: D[row][col] needs be[row], row = half*4+reg.
        f32x4 cb = *(const f32x4*)&bias_s[mt*16 + half*4];

        f32x4 d[9];
#pragma unroll
        for (int u = 0; u < 9; u++)
            d[u] = __builtin_amdgcn_mfma_f32_16x16x32_bf16(af, bfr[u], cb, 0, 0, 0);

        float p0=0.f, p1=0.f, p2=0.f, p3=0.f;
#pragma unroll
        for (int u = 0; u < 9; u++) {
            p0 += fmaxf(d[u][0], 0.f);
            p1 += fmaxf(d[u][1], 0.f);
            p2 += fmaxf(d[u][2], 0.f);
            p3 += fmaxf(d[u][3], 0.f);
        }
        // reduce over the 16 columns (lanes sharing l>>4)
#pragma unroll
        for (int msk = 1; msk < 16; msk <<= 1) {
            p0 += __shfl_xor(p0, msk);
            p1 += __shfl_xor(p1, msk);
            p2 += __shfl_xor(p2, msk);
            p3 += __shfl_xor(p3, msk);
        }
        if (col == 0) {
            f32x4 pv = {p0, p1, p2, p3};        // rows m = mt*16 + half*4 + r
            *(f32x4*)&psum[w*400 + mt*16 + half*4] = pv;
        }
    }
    __syncthreads();

    const float inv = 1.f / 676.f;              // 26x26 pool incl. 100 border px
    for (int m = t; m < 400; m += 256) {
        float s = psum[0*400+m] + psum[1*400+m] + psum[2*400+m] + psum[3*400+m];
        float be = bias_s[m];
        pooled[(i*2+b)*6400 + k*400 + m] = (s + 100.f * fmaxf(be, 0.f)) * inv;
    }
}

__global__ __launch_bounds__(256) void k3_aff(const float* __restrict__ pooled,
                                              float* __restrict__ aff)
{
    __shared__ float th[400];
    __shared__ float parts[256];
    int bid = blockIdx.x;           // i*2 + b
    int i = bid >> 1;
    int t = threadIdx.x;
    const float* pb = &pooled[bid*6400];
    for (int idx = t; idx < 400; idx += 256) th[idx] = pb[i*400 + idx];
    __syncthreads();
    int l = t >> 4, p = t & 15;
    float sum = 0.f;
    const float* pl = &pb[l*400];
    for (int m = p*25; m < p*25 + 25; m++) sum = fmaf(th[m], pl[m], sum);
    parts[t] = sum;
    __syncthreads();
    if (t < 16) {
        float s = 0.f;
        for (int pp = 0; pp < 16; pp++) s += parts[t*16 + pp];
        aff[bid*16 + t] = s * (1.f/16.f);
    }
}

__global__ __launch_bounds__(256) void k4_out(const float* __restrict__ h1f,
                                              const float* __restrict__ aff,
                                              float* __restrict__ out)
{
    __shared__ float a0[16], a1[16];
    int bid = blockIdx.x;           // i*32 + q*16 + cg
    int i = bid >> 5, q = (bid >> 4) & 1, cg = bid & 15;
    int t = threadIdx.x;
    if (t < 16) a0[t] = aff[(i*2+0)*16 + t];
    else if (t < 32) a1[t-16] = aff[(i*2+1)*16 + (t-16)];
    __syncthreads();
    const float* hb = &h1f[((i*2+q)*256 + cg)*576];
    int ch = i*32 + q*16 + cg;
    for (int s = t; s < 576; s += 256) {
        float acc0 = 0.f, acc1 = 0.f;
#pragma unroll
        for (int k = 0; k < 16; k++) {
            float v = hb[k*9216 + s];
            acc0 = fmaf(a0[k], v, acc0);
            acc1 = fmaf(a1[k], v, acc1);
        }
        out[ch*576 + s]         = acc0;
        out[(512 + ch)*576 + s] = acc1;
    }
}

extern "C" void kernel_launch(void* const* d_in, const int* in_sizes, int n_in,
                              void* d_out, int out_size, void* d_ws, size_t ws_size,
                              hipStream_t stream)
{
    const float* x  = (const float*)d_in[0];
    const float* W1 = (const float*)d_in[1];
    const float* g1 = (const float*)d_in[2];
    const float* b1 = (const float*)d_in[3];
    const float* m1 = (const float*)d_in[4];
    const float* v1 = (const float*)d_in[5];
    const float* W2 = (const float*)d_in[6];
    const float* g2 = (const float*)d_in[7];
    const float* b2 = (const float*)d_in[8];
    const float* m2 = (const float*)d_in[9];
    const float* v2 = (const float*)d_in[10];

    float* h1f    = (float*)d_ws;
    float* pooled = h1f + 16*2*256*576;     // +4,718,592 floats
    float* aff    = pooled + 16*2*6400;     // +204,800 floats

    float* out = (float*)d_out;

    hipLaunchKernelGGL(k1_conv_bn,   dim3(512), dim3(384), 0, stream,
                       x, W1, g1, b1, m1, v1, h1f);
    hipLaunchKernelGGL(k2_pool_mfma, dim3(512), dim3(256), 0, stream,
                       h1f, W2, g2, b2, m2, v2, pooled);
    hipLaunchKernelGGL(k3_aff,       dim3(32),  dim3(256), 0, stream,
                       pooled, aff);
    hipLaunchKernelGGL(k4_out,       dim3(512), dim3(256), 0, stream,
                       h1f, aff, out);
}

// Round 6
// 126.547 us; speedup vs baseline: 1.5602x; 1.1988x over previous
//
#include <hip/hip_runtime.h>
#include <hip/hip_bf16.h>

// Shapes: B=2, C=256, H=W=24 (HW=576), G=16, Cg=16, GRID=25, AC=6400, Mg=400
// Inputs fp32, output fp32.
// ws layout (fp32): h1f[16*2*256*576] | pooled[16*2*6400] | aff[16*2*16]

typedef __attribute__((ext_vector_type(8))) short short8;
typedef __attribute__((ext_vector_type(4))) short short4v;
typedef __attribute__((ext_vector_type(4))) float f32x4;

static __device__ __forceinline__ short f2bf(float x) {
    unsigned u = __float_as_uint(x);
    unsigned r = (u + 0x7fffu + ((u >> 16) & 1u)) >> 16;   // RNE
    return (short)r;
}

// 3x3 grouped conv + BN + ReLU as implicit GEMM on MFMA.
// Per block (i,b,g): D(16co x 576px) = W'(16 x 144) * im2col(144 x 576) + bias.
// K = 144 (16ci x 9taps) padded to 160 = 5 K-steps of 32 (2 taps per step).
__global__ __launch_bounds__(256) void k1_conv_mfma(
    const float* __restrict__ xin,
    const float* __restrict__ W1,
    const float* __restrict__ g1, const float* __restrict__ b1,
    const float* __restrict__ m1, const float* __restrict__ v1,
    float* __restrict__ h1f)
{
    __shared__ __align__(16) short xs[27*26*24];  // [row][col][ci pitch 24], bf16, zero-pad
    __shared__ __align__(16) short wA[5*16*40];   // [kk][co][k pitch 40], bf16, W1*sc
    __shared__ float scale_s[16], bias_s[16];

    int bid = blockIdx.x;                         // i*32 + b*16 + g
    int i = bid >> 5, b = (bid >> 4) & 1, g = bid & 15;
    int t = threadIdx.x;

    // --- phase A: zero xs; fold BN params ---
    int* xz = (int*)xs;
    for (int idx = t; idx < 27*26*12; idx += 256) xz[idx] = 0;
    if (t < 16) {
        int c = i*256 + g*16 + t;
        float sc = g1[c] * rsqrtf(v1[c] + 1e-5f);
        scale_s[t] = sc;
        bias_s[t]  = b1[c] - m1[c] * sc;
    }
    __syncthreads();

    // --- phase B: stage image (bf16, pixel-major) + scaled weights ---
    const float* xb = &xin[(b*256 + g*16)*576];
    for (int idx = t; idx < 9216; idx += 256) {
        int ci = idx / 576; int s = idx - ci*576;
        int y = s / 24; int x = s - y*24;
        xs[((y+1)*26 + (x+1))*24 + ci] = f2bf(xb[idx]);
    }
    const float* wb = &W1[(i*256 + g*16)*144];    // [co][ci][9]
    for (int idx = t; idx < 2560; idx += 256) {
        int kk = idx >> 9, rem = idx & 511, co = rem >> 5, k = rem & 31;
        int tap = 2*kk + (k >> 4), ci = k & 15;
        float val = (tap < 9) ? wb[co*144 + ci*9 + tap] * scale_s[co] : 0.f;
        wA[(kk*16 + co)*40 + k] = f2bf(val);
    }
    __syncthreads();

    // --- phase C: 9 pixel-tiles per wave, 5 MFMA each ---
    int l = t & 63, w = t >> 6;
    int quad = l >> 4, col = l & 15;
    int ci0 = (quad & 1) * 8;

    short8 afr[5];
#pragma unroll
    for (int kk = 0; kk < 5; kk++)
        afr[kk] = *(const short8*)&wA[(kk*16 + col)*40 + quad*8];

    f32x4 cb = *(const f32x4*)&bias_s[quad*4];

    // tap offsets in shorts (pitch 24, row stride 26*24): even taps for quads 0-1,
    // odd taps for quads 2-3 (tap = 2kk + (quad>=2)); tap 9 hits zeroed A.
    const int offE[5] = {0, 48, 648, 1248, 1296};     // taps 0,2,4,6,8
    const int offO[5] = {24, 624, 672, 1272, 1872};   // taps 1,3,5,7,9
    int off[5];
#pragma unroll
    for (int kk = 0; kk < 5; kk++) off[kk] = (quad >= 2) ? offO[kk] : offE[kk];

    float* hout = &h1f[((i*2 + b)*256 + g*16)*576];
#pragma unroll 3
    for (int tt = 0; tt < 9; tt++) {
        int tile = w*9 + tt;
        int s = tile*16 + col;
        int y = s / 24; int x = s - y*24;
        int base = (y*26 + x)*24 + ci0;
        f32x4 acc = cb;
#pragma unroll
        for (int kk = 0; kk < 5; kk++) {
            short8 bf = *(const short8*)&xs[base + off[kk]];
            acc = __builtin_amdgcn_mfma_f32_16x16x32_bf16(afr[kk], bf, acc, 0, 0, 0);
        }
#pragma unroll
        for (int r = 0; r < 4; r++)
            hout[(quad*4 + r)*576 + s] = fmaxf(acc[r], 0.f);
    }
}

// Fused grouped 1x1 conv (pad=1) + BN + ReLU + 26x26 avg-pool via bf16 MFMA.
// Per block (i,b,k): D = W2'(400x16) * h(16x576) + bias; pool = sum_s relu(D).
__global__ __launch_bounds__(256) void k2_pool_mfma(
    const float* __restrict__ h1f,
    const float* __restrict__ W2,
    const float* __restrict__ g2, const float* __restrict__ b2,
    const float* __restrict__ m2, const float* __restrict__ v2,
    float* __restrict__ pooled)
{
    __shared__ __align__(16) short hsb[576*20];   // [s][j], pitch 20 shorts
    __shared__ __align__(16) short wlb[400*16];   // [m][j] bf16, W2*s2
    __shared__ __align__(16) float psum[4*400];   // per-wave pool partials
    __shared__ __align__(16) float bias_s[400];   // folded BN bias per m

    int bid = blockIdx.x;                        // i*32 + b*16 + k
    int i = bid >> 5, b = (bid >> 4) & 1, k = bid & 15;
    int t = threadIdx.x;

    const float* hbase = &h1f[((i*2 + b)*256 + k*16)*576];
    for (int idx = t; idx < 9216; idx += 256) {
        int j = idx / 576; int s = idx - j*576;
        hsb[s*20 + j] = f2bf(hbase[idx]);
    }
    for (int m = t; m < 400; m += 256) {
        int o = i*6400 + k*400 + m;
        float s2 = g2[o] * rsqrtf(v2[o] + 1e-5f);
        bias_s[m] = b2[o] - m2[o] * s2;
        const float4* wr = (const float4*)&W2[o*16];
#pragma unroll
        for (int q = 0; q < 4; q++) {
            float4 wv = wr[q];
            wlb[m*16 + q*4 + 0] = f2bf(wv.x * s2);
            wlb[m*16 + q*4 + 1] = f2bf(wv.y * s2);
            wlb[m*16 + q*4 + 2] = f2bf(wv.z * s2);
            wlb[m*16 + q*4 + 3] = f2bf(wv.w * s2);
        }
    }
    __syncthreads();

    int l = t & 63, w = t >> 6;
    int half = l >> 4;          // quad 0..3 ; quads 2,3 are K-padding (zero)
    int col  = l & 15;

    short8 bfr[9];
#pragma unroll
    for (int u = 0; u < 9; u++) {
        if (l < 32) {
            const short* p = &hsb[((w*9 + u)*16 + col)*20 + half*8];
            short4v lo = *(const short4v*)p;
            short4v hi = *(const short4v*)(p + 4);
            short8 f; f[0]=lo.x; f[1]=lo.y; f[2]=lo.z; f[3]=lo.w;
                      f[4]=hi.x; f[5]=hi.y; f[6]=hi.z; f[7]=hi.w;
            bfr[u] = f;
        } else {
            bfr[u] = (short8)0;
        }
    }

    for (int mt = 0; mt < 25; mt++) {
        short8 af = (short8)0;
        if (l < 32)
            af = *(const short8*)&wlb[(mt*16 + col)*16 + half*8];

        f32x4 cb = *(const f32x4*)&bias_s[mt*16 + half*4];

        f32x4 d[9];
#pragma unroll
        for (int u = 0; u < 9; u++)
            d[u] = __builtin_amdgcn_mfma_f32_16x16x32_bf16(af, bfr[u], cb, 0, 0, 0);

        float p0=0.f, p1=0.f, p2=0.f, p3=0.f;
#pragma unroll
        for (int u = 0; u < 9; u++) {
            p0 += fmaxf(d[u][0], 0.f);
            p1 += fmaxf(d[u][1], 0.f);
            p2 += fmaxf(d[u][2], 0.f);
            p3 += fmaxf(d[u][3], 0.f);
        }
#pragma unroll
        for (int msk = 1; msk < 16; msk <<= 1) {
            p0 += __shfl_xor(p0, msk);
            p1 += __shfl_xor(p1, msk);
            p2 += __shfl_xor(p2, msk);
            p3 += __shfl_xor(p3, msk);
        }
        if (col == 0) {
            f32x4 pv = {p0, p1, p2, p3};
            *(f32x4*)&psum[w*400 + mt*16 + half*4] = pv;
        }
    }
    __syncthreads();

    const float inv = 1.f / 676.f;
    for (int m = t; m < 400; m += 256) {
        float s = psum[0*400+m] + psum[1*400+m] + psum[2*400+m] + psum[3*400+m];
        float be = bias_s[m];
        pooled[(i*2+b)*6400 + k*400 + m] = (s + 100.f * fmaxf(be, 0.f)) * inv;
    }
}

__global__ __launch_bounds__(256) void k3_aff(const float* __restrict__ pooled,
                                              float* __restrict__ aff)
{
    __shared__ float th[400];
    __shared__ float parts[256];
    int bid = blockIdx.x;           // i*2 + b
    int i = bid >> 1;
    int t = threadIdx.x;
    const float* pb = &pooled[bid*6400];
    for (int idx = t; idx < 400; idx += 256) th[idx] = pb[i*400 + idx];
    __syncthreads();
    int l = t >> 4, p = t & 15;
    float sum = 0.f;
    const float* pl = &pb[l*400];
    for (int m = p*25; m < p*25 + 25; m++) sum = fmaf(th[m], pl[m], sum);
    parts[t] = sum;
    __syncthreads();
    if (t < 16) {
        float s = 0.f;
        for (int pp = 0; pp < 16; pp++) s += parts[t*16 + pp];
        aff[bid*16 + t] = s * (1.f/16.f);
    }
}

__global__ __launch_bounds__(256) void k4_out(const float* __restrict__ h1f,
                                              const float* __restrict__ aff,
                                              float* __restrict__ out)
{
    __shared__ float a0[16], a1[16];
    int bid = blockIdx.x;           // i*32 + q*16 + cg
    int i = bid >> 5, q = (bid >> 4) & 1, cg = bid & 15;
    int t = threadIdx.x;
    if (t < 16) a0[t] = aff[(i*2+0)*16 + t];
    else if (t < 32) a1[t-16] = aff[(i*2+1)*16 + (t-16)];
    __syncthreads();
    const float* hb = &h1f[((i*2+q)*256 + cg)*576];
    int ch = i*32 + q*16 + cg;
    for (int s = t; s < 576; s += 256) {
        float acc0 = 0.f, acc1 = 0.f;
#pragma unroll
        for (int k = 0; k < 16; k++) {
            float v = hb[k*9216 + s];
            acc0 = fmaf(a0[k], v, acc0);
            acc1 = fmaf(a1[k], v, acc1);
        }
        out[ch*576 + s]         = acc0;
        out[(512 + ch)*576 + s] = acc1;
    }
}

extern "C" void kernel_launch(void* const* d_in, const int* in_sizes, int n_in,
                              void* d_out, int out_size, void* d_ws, size_t ws_size,
                              hipStream_t stream)
{
    const float* x  = (const float*)d_in[0];
    const float* W1 = (const float*)d_in[1];
    const float* g1 = (const float*)d_in[2];
    const float* b1 = (const float*)d_in[3];
    const float* m1 = (const float*)d_in[4];
    const float* v1 = (const float*)d_in[5];
    const float* W2 = (const float*)d_in[6];
    const float* g2 = (const float*)d_in[7];
    const float* b2 = (const float*)d_in[8];
    const float* m2 = (const float*)d_in[9];
    const float* v2 = (const float*)d_in[10];

    float* h1f    = (float*)d_ws;
    float* pooled = h1f + 16*2*256*576;     // +4,718,592 floats
    float* aff    = pooled + 16*2*6400;     // +204,800 floats

    float* out = (float*)d_out;

    hipLaunchKernelGGL(k1_conv_mfma, dim3(512), dim3(256), 0, stream,
                       x, W1, g1, b1, m1, v1, h1f);
    hipLaunchKernelGGL(k2_pool_mfma, dim3(512), dim3(256), 0, stream,
                       h1f, W2, g2, b2, m2, v2, pooled);
    hipLaunchKernelGGL(k3_aff,       dim3(32),  dim3(256), 0, stream,
                       pooled, aff);
    hipLaunchKernelGGL(k4_out,       dim3(512), dim3(256), 0, stream,
                       h1f, aff, out);
}